// Round 3
// baseline (247.791 us; speedup 1.0000x reference)
//
#include <hip/hip_runtime.h>
#include <math.h>

#define N_DIA 48
#define NTOT  3072     // N utterances
#define DD    512      // D == H
#define M3    9216     // 3N
#define SEG   ((size_t)NTOT * DD)

#define SCALE_F 0.99999f
#define PI_F    3.14159274101257324f

typedef __attribute__((ext_vector_type(8))) short frag8;
typedef __attribute__((ext_vector_type(4))) float f32x4;

__device__ __forceinline__ float ang_sim(float cs) {
    float cc = cs * SCALE_F;
    cc = fminf(fmaxf(cc, -SCALE_F), SCALE_F);
    return 1.0f - acosf(cc) / PI_F;
}
__device__ __forceinline__ unsigned short f2bf(float x) {
    union { float f; unsigned int u; } c; c.f = x;
    unsigned int r = c.u + 0x7fffu + ((c.u >> 16) & 1u);
    return (unsigned short)(r >> 16);
}
__device__ __forceinline__ float bf2f(unsigned short h) {
    union { unsigned int u; float f; } c; c.u = ((unsigned int)h) << 16;
    return c.f;
}
__device__ __forceinline__ void gload16(const unsigned short* g, unsigned short* s) {
    __builtin_amdgcn_global_load_lds(
        (const __attribute__((address_space(1))) unsigned int*)g,
        (__attribute__((address_space(3))) unsigned int*)s, 16, 0, 0);
}

// ---------- K_pre_wt: (blocks 0..767) per-utterance pre; (768..1535) W -> bf16 [n][k] ----------
__global__ __launch_bounds__(256) void k_pre_wt(
    const float* __restrict__ a, const float* __restrict__ v,
    const float* __restrict__ l, const float* __restrict__ qmask,
    const float* __restrict__ Wspk, const float* __restrict__ W0,
    const float* __restrict__ Wg,
    float* __restrict__ out, unsigned short* __restrict__ xb,
    float* __restrict__ invn, float* __restrict__ cross,
    unsigned short* __restrict__ Wt)
{
    __shared__ float tile[32][33];
    int b = blockIdx.x;
    if (b < 768) {
        int wv = threadIdx.x >> 6, t = threadIdx.x & 63;
        int i = b * 4 + wv;                 // utterance, one wave each
        int pos = i & 63, dia = i >> 6;
        int qb = (pos * N_DIA + dia) * 2;
        float q0 = qmask[qb], q1 = qmask[qb + 1];
        int spk = (q0 >= q1) ? 0 : 1;
        const float4* av4 = (const float4*)(a + (size_t)i * DD);
        const float4* vv4 = (const float4*)(v + (size_t)i * DD);
        const float4* lv4 = (const float4*)(l + (size_t)i * DD);
        const float4* wv4 = (const float4*)(Wspk + (size_t)spk * DD);
        float* ob = out + (size_t)i * 3072;
        float saa = 0, svv = 0, sll = 0, sav = 0, sal = 0, svl = 0;
#pragma unroll
        for (int e = 0; e < 2; e++) {
            int idx = t * 2 + e;
            float4 xa = av4[idx], xv = vv4[idx], xd = lv4[idx], xw = wv4[idx];
            float4 xL = make_float4(xd.x + xw.x, xd.y + xw.y, xd.z + xw.z, xd.w + xw.w);
            *(float4*)(ob + idx * 4)        = xa;
            *(float4*)(ob + 1024 + idx * 4) = xv;
            *(float4*)(ob + 2048 + idx * 4) = xL;
            ushort4 ya, yv, yl;
            ya.x = f2bf(xa.x); ya.y = f2bf(xa.y); ya.z = f2bf(xa.z); ya.w = f2bf(xa.w);
            yv.x = f2bf(xv.x); yv.y = f2bf(xv.y); yv.z = f2bf(xv.z); yv.w = f2bf(xv.w);
            yl.x = f2bf(xL.x); yl.y = f2bf(xL.y); yl.z = f2bf(xL.z); yl.w = f2bf(xL.w);
            *(ushort4*)(xb + (size_t)i * DD + idx * 4) = ya;
            *(ushort4*)(xb + SEG + (size_t)i * DD + idx * 4) = yv;
            *(ushort4*)(xb + 2 * SEG + (size_t)i * DD + idx * 4) = yl;
            saa += xa.x * xa.x + xa.y * xa.y + xa.z * xa.z + xa.w * xa.w;
            svv += xv.x * xv.x + xv.y * xv.y + xv.z * xv.z + xv.w * xv.w;
            sll += xL.x * xL.x + xL.y * xL.y + xL.z * xL.z + xL.w * xL.w;
            sav += xa.x * xv.x + xa.y * xv.y + xa.z * xv.z + xa.w * xv.w;
            sal += xa.x * xL.x + xa.y * xL.y + xa.z * xL.z + xa.w * xL.w;
            svl += xv.x * xL.x + xv.y * xL.y + xv.z * xL.z + xv.w * xL.w;
        }
#pragma unroll
        for (int off = 32; off; off >>= 1) {
            saa += __shfl_down(saa, off, 64);
            svv += __shfl_down(svv, off, 64);
            sll += __shfl_down(sll, off, 64);
            sav += __shfl_down(sav, off, 64);
            sal += __shfl_down(sal, off, 64);
            svl += __shfl_down(svl, off, 64);
        }
        if (t == 0) {
            float ina = 1.0f / sqrtf(saa);
            float inv_ = 1.0f / sqrtf(svv);
            float inl = 1.0f / sqrtf(sll);
            invn[i] = ina; invn[NTOT + i] = inv_; invn[2 * NTOT + i] = inl;
            cross[i]            = ang_sim(sav * ina * inv_);
            cross[NTOT + i]     = ang_sim(sal * ina * inl);
            cross[2 * NTOT + i] = ang_sim(svl * inv_ * inl);
        }
    } else {
        int idx = b - 768;
        int mm = idx >> 8;
        int by = (idx >> 4) & 15, bx = idx & 15;
        const float* W = (mm == 0) ? W0 : Wg + (size_t)(mm - 1) * DD * DD;
        int t = threadIdx.x, tx = t & 31, ty = t >> 5;
#pragma unroll
        for (int q = 0; q < 4; q++) {
            int k = by * 32 + ty + q * 8;
            tile[ty + q * 8][tx] = W[(size_t)k * DD + bx * 32 + tx];
        }
        __syncthreads();
#pragma unroll
        for (int q = 0; q < 4; q++) {
            int n = bx * 32 + ty + q * 8;
            Wt[(size_t)mm * DD * DD + (size_t)n * DD + by * 32 + tx] = f2bf(tile[tx][ty + q * 8]);
        }
    }
}

// ---------- fused013: blocks [0,288): 32-row tiles, h0(LDS-only) -> G1(rows+T) + P02(rows)
//            blocks [288,432): gram (verbatim) ----------
__global__ __launch_bounds__(256) void k_fused013(
    const unsigned short* __restrict__ xb, const unsigned short* __restrict__ Wt,
    const float* __restrict__ bias,
    unsigned short* __restrict__ G1r, unsigned short* __restrict__ G1T,
    unsigned short* __restrict__ P02,
    const float* __restrict__ invn, const float* __restrict__ cross,
    float* __restrict__ blk, float* __restrict__ dinv,
    float th1, float th2)
{
    __shared__ __align__(16) char smem[65536];
    int b = blockIdx.x;
    int t = threadIdx.x, lane = t & 63, wv = t >> 6;
    int rsel = lane & 15, quad = lane >> 4;

    if (b >= 288) {
        // ---- gram flavor (verbatim from verified k_gram_mfma) ----
        unsigned short* Xs = (unsigned short*)smem;              // 64 KB
        int g = b - 288;
        int d = g % N_DIA, m = g / N_DIA;
        int mrow = m * NTOT + d * 64;
        const unsigned short* src = xb + (size_t)mrow * DD;
        int sunit = ((t & 3) ^ ((t >> 2) & 3)) * 8;
#pragma unroll
        for (int c = 0; c < 16; c++) {
            gload16(src + (size_t)(t >> 2) * DD + c * 32 + sunit,
                    &Xs[c * 2048 + wv * 512]);
        }
        __syncthreads();
        int sq = (quad ^ (rsel & 3)) * 8;
        f32x4 acc[4];
#pragma unroll
        for (int j = 0; j < 4; j++) acc[j] = (f32x4){0.f, 0.f, 0.f, 0.f};
#pragma unroll
        for (int c = 0; c < 16; c++) {
            const unsigned short* base = &Xs[c * 2048];
            frag8 bf[4];
#pragma unroll
            for (int j = 0; j < 4; j++)
                bf[j] = *(const frag8*)&base[(j * 16 + rsel) * 32 + sq];
            frag8 af = *(const frag8*)&base[(wv * 16 + rsel) * 32 + sq];
#pragma unroll
            for (int j = 0; j < 4; j++)
                acc[j] = __builtin_amdgcn_mfma_f32_16x16x32_bf16(af, bf[j], acc[j], 0, 0, 0);
        }
        size_t bbase = (size_t)(m * N_DIA + d) * 4096;
        int rowl0 = wv * 16 + quad * 4;
        float ir[4], rs[4] = {0.f, 0.f, 0.f, 0.f};
#pragma unroll
        for (int r = 0; r < 4; r++) ir[r] = invn[mrow + rowl0 + r];
#pragma unroll
        for (int j = 0; j < 4; j++) {
            int coll = j * 16 + rsel;
            float ic = invn[mrow + coll];
#pragma unroll
            for (int r = 0; r < 4; r++) {
                float sim = ang_sim(acc[j][r] * ir[r] * ic);
                blk[bbase + (size_t)(rowl0 + r) * 64 + coll] = sim;
                rs[r] += sim;
            }
        }
#pragma unroll
        for (int off = 8; off; off >>= 1)
#pragma unroll
            for (int r = 0; r < 4; r++) rs[r] += __shfl_down(rs[r], off, 16);
        if (rsel == 0) {
#pragma unroll
            for (int r = 0; r < 4; r++) {
                int gi = d * 64 + rowl0 + r;
                float c1, c2;
                if (m == 0)      { c1 = cross[gi];        c2 = cross[NTOT + gi]; }
                else if (m == 1) { c1 = cross[gi];        c2 = cross[2 * NTOT + gi]; }
                else             { c1 = cross[NTOT + gi]; c2 = cross[2 * NTOT + gi]; }
                dinv[m * NTOT + gi] = 1.0f / sqrtf(rs[r] + c1 + c2);
            }
        }
        return;
    }

    // ---- fused flavor: 32 rows x 512 cols; W streamed from L2 as fragments ----
    unsigned short* Xs  = (unsigned short*)smem;            // [32][512] swizzled, 32 KB
    unsigned short* H0s = (unsigned short*)(smem + 32768);  // [32][512] swizzled, 32 KB
    int mbase = b * 32;

    // stage x-tile: one row per wave-round, source pre-swizzled (u ^ ((row&7)<<2))
#pragma unroll
    for (int r = 0; r < 8; r++) {
        int row = r * 4 + wv;
        int us = lane ^ ((row & 7) << 2);
        gload16(xb + (size_t)(mbase + row) * DD + us * 8, Xs + row * 512);
    }
    __syncthreads();

    const unsigned short* W0t = Wt;
    const unsigned short* W1t = Wt + (size_t)DD * DD;
    const unsigned short* W2t = Wt + (size_t)2 * DD * DD;

    f32x4 acc[16];

    // ---- phase A: h0 = relu(x @ W0 + b0) -> H0s (LDS only) ----
#pragma unroll
    for (int z = 0; z < 16; z++) acc[z] = (f32x4){0.f, 0.f, 0.f, 0.f};
#pragma unroll 4
    for (int kt = 0; kt < 16; kt++) {
        frag8 af[2];
#pragma unroll
        for (int i = 0; i < 2; i++) {
            int row = i * 16 + rsel;
            int u = kt * 4 + quad;
            af[i] = *(const frag8*)&Xs[row * 512 + ((u ^ ((row & 7) << 2)) << 3)];
        }
#pragma unroll
        for (int j = 0; j < 8; j++) {
            frag8 bf = *(const frag8*)(W0t + (size_t)(wv * 128 + j * 16 + rsel) * DD + kt * 32 + quad * 8);
#pragma unroll
            for (int i = 0; i < 2; i++)
                acc[i * 8 + j] = __builtin_amdgcn_mfma_f32_16x16x32_bf16(af[i], bf, acc[i * 8 + j], 0, 0, 0);
        }
    }
#pragma unroll
    for (int i = 0; i < 2; i++)
#pragma unroll
        for (int j = 0; j < 8; j++) {
            int col = wv * 128 + j * 16 + rsel;
            float bv = bias[col];
#pragma unroll
            for (int rr = 0; rr < 4; rr++) {
                int row = i * 16 + quad * 4 + rr;
                float x = fmaxf(acc[i * 8 + j][rr] + bv, 0.f);
                H0s[row * 512 + (((col >> 3) ^ ((row & 7) << 2)) << 3) + (col & 7)] = f2bf(x);
            }
        }
    __syncthreads();

    // ---- phase B: G1 = th1*(h0@W1) + (1-th1)*h0 -> G1r rows + G1T ----
#pragma unroll
    for (int z = 0; z < 16; z++) acc[z] = (f32x4){0.f, 0.f, 0.f, 0.f};
#pragma unroll 4
    for (int kt = 0; kt < 16; kt++) {
        frag8 af[2];
#pragma unroll
        for (int i = 0; i < 2; i++) {
            int row = i * 16 + rsel;
            int u = kt * 4 + quad;
            af[i] = *(const frag8*)&H0s[row * 512 + ((u ^ ((row & 7) << 2)) << 3)];
        }
#pragma unroll
        for (int j = 0; j < 8; j++) {
            frag8 bf = *(const frag8*)(W1t + (size_t)(wv * 128 + j * 16 + rsel) * DD + kt * 32 + quad * 8);
#pragma unroll
            for (int i = 0; i < 2; i++)
                acc[i * 8 + j] = __builtin_amdgcn_mfma_f32_16x16x32_bf16(af[i], bf, acc[i * 8 + j], 0, 0, 0);
        }
    }
    {
        float omt = 1.0f - th1;
#pragma unroll
        for (int i = 0; i < 2; i++)
#pragma unroll
            for (int j = 0; j < 8; j++) {
                int col = wv * 128 + j * 16 + rsel;
                float vv[4];
#pragma unroll
                for (int rr = 0; rr < 4; rr++) {
                    int row = i * 16 + quad * 4 + rr;
                    float h0v = bf2f(H0s[row * 512 + (((col >> 3) ^ ((row & 7) << 2)) << 3) + (col & 7)]);
                    vv[rr] = th1 * acc[i * 8 + j][rr] + omt * h0v;
                    G1r[(size_t)(mbase + row) * DD + col] = f2bf(vv[rr]);
                }
                ushort4 w4;
                w4.x = f2bf(vv[0]); w4.y = f2bf(vv[1]);
                w4.z = f2bf(vv[2]); w4.w = f2bf(vv[3]);
                *(ushort4*)(G1T + (size_t)col * M3 + mbase + i * 16 + quad * 4) = w4;
            }
    }

    // ---- phase C: P02 = th2*(h0@W2) + (1-th2)*h0 -> P02 rows ----
#pragma unroll
    for (int z = 0; z < 16; z++) acc[z] = (f32x4){0.f, 0.f, 0.f, 0.f};
#pragma unroll 4
    for (int kt = 0; kt < 16; kt++) {
        frag8 af[2];
#pragma unroll
        for (int i = 0; i < 2; i++) {
            int row = i * 16 + rsel;
            int u = kt * 4 + quad;
            af[i] = *(const frag8*)&H0s[row * 512 + ((u ^ ((row & 7) << 2)) << 3)];
        }
#pragma unroll
        for (int j = 0; j < 8; j++) {
            frag8 bf = *(const frag8*)(W2t + (size_t)(wv * 128 + j * 16 + rsel) * DD + kt * 32 + quad * 8);
#pragma unroll
            for (int i = 0; i < 2; i++)
                acc[i * 8 + j] = __builtin_amdgcn_mfma_f32_16x16x32_bf16(af[i], bf, acc[i * 8 + j], 0, 0, 0);
        }
    }
    {
        float omt = 1.0f - th2;
#pragma unroll
        for (int i = 0; i < 2; i++)
#pragma unroll
            for (int j = 0; j < 8; j++) {
                int col = wv * 128 + j * 16 + rsel;
#pragma unroll
                for (int rr = 0; rr < 4; rr++) {
                    int row = i * 16 + quad * 4 + rr;
                    float h0v = bf2f(H0s[row * 512 + (((col >> 3) ^ ((row & 7) << 2)) << 3) + (col & 7)]);
                    P02[(size_t)(mbase + row) * DD + col] = f2bf(th2 * acc[i * 8 + j][rr] + omt * h0v);
                }
            }
    }
}

// ---------- GEMM: 64(M) x 128(N) tile, dbuf LDS, swizzled, coalesced LDS epilogue ----------
__global__ __launch_bounds__(256) void k_gemm(
    const unsigned short* __restrict__ A, const unsigned short* __restrict__ W,
    const float* __restrict__ bias,
    unsigned short* __restrict__ oRows, unsigned short* __restrict__ oT,
    float theta, int mode,
    const unsigned short* __restrict__ A2, unsigned short* __restrict__ oRows2)
{
    __shared__ __align__(16) char smem[53248];
    unsigned short* const As0 = (unsigned short*)smem;            // 4 KB
    unsigned short* const As1 = (unsigned short*)(smem + 4096);
    unsigned short* const Bs0 = (unsigned short*)(smem + 8192);   // 8 KB
    unsigned short* const Bs1 = (unsigned short*)(smem + 16384);
    unsigned short* const tH  = (unsigned short*)smem;            // [64][136]
    unsigned short* const tR  = (unsigned short*)(smem + 17408);  // [64][136]
    unsigned short* const tT  = (unsigned short*)(smem + 34816);  // [128][72]

    int t = threadIdx.x, lane = t & 63, wv = t >> 6;
    int bx = blockIdx.x, by = blockIdx.y;
    const unsigned short* Ap = A;
    unsigned short* oR = oRows;
    unsigned short* oTp = oT;
    if (by >= 144) { Ap = A2; oR = oRows2; oTp = nullptr; by -= 144; }
    int mbase = by * 64, nbase = bx * 128;
    int srow = lane >> 2;
    int scol = (((lane & 3) ^ (srow & 3)) * 8);
    int rsel = lane & 15, quad = lane >> 4;
    int sq = (quad ^ (rsel & 3)) * 8;

    const unsigned short* Ag  = Ap + (size_t)(mbase + wv * 16 + srow) * DD + scol;
    const unsigned short* Bg0 = W  + (size_t)(nbase + wv * 32 + srow) * DD + scol;
    const unsigned short* Bg1 = W  + (size_t)(nbase + wv * 32 + 16 + srow) * DD + scol;

    f32x4 acc[8];
#pragma unroll
    for (int i = 0; i < 8; i++) acc[i] = (f32x4){0.f, 0.f, 0.f, 0.f};

    gload16(Ag,  As0 + wv * 512);
    gload16(Bg0, Bs0 + wv * 1024);
    gload16(Bg1, Bs0 + wv * 1024 + 512);

#pragma unroll
    for (int kt = 0; kt < 16; kt++) {
        __syncthreads();
        const unsigned short* Ac = (kt & 1) ? As1 : As0;
        const unsigned short* Bc = (kt & 1) ? Bs1 : Bs0;
        if (kt < 15) {
            unsigned short* An = (kt & 1) ? As0 : As1;
            unsigned short* Bn = (kt & 1) ? Bs0 : Bs1;
            gload16(Ag + (kt + 1) * 32,  An + wv * 512);
            gload16(Bg0 + (kt + 1) * 32, Bn + wv * 1024);
            gload16(Bg1 + (kt + 1) * 32, Bn + wv * 1024 + 512);
        }
        frag8 af[4], bfr[2];
#pragma unroll
        for (int i = 0; i < 4; i++)
            af[i] = *(const frag8*)&Ac[(i * 16 + rsel) * 32 + sq];
#pragma unroll
        for (int j = 0; j < 2; j++)
            bfr[j] = *(const frag8*)&Bc[(wv * 32 + j * 16 + rsel) * 32 + sq];
#pragma unroll
        for (int i = 0; i < 4; i++)
#pragma unroll
            for (int j = 0; j < 2; j++)
                acc[i * 2 + j] = __builtin_amdgcn_mfma_f32_16x16x32_bf16(
                    af[i], bfr[j], acc[i * 2 + j], 0, 0, 0);
    }
    __syncthreads();

    int r = t >> 2, c0 = (t & 3) * 32;
    if (mode == 1) {
        const unsigned short* srcA = Ap + (size_t)(mbase + r) * DD + nbase + c0;
#pragma unroll
        for (int u = 0; u < 4; u++)
            *(uint4*)&tH[r * 136 + c0 + u * 8] = *(const uint4*)(srcA + u * 8);
        __syncthreads();
    }
    float omt = 1.0f - theta;
#pragma unroll
    for (int i = 0; i < 4; i++)
#pragma unroll
        for (int j = 0; j < 2; j++) {
            int cl = wv * 32 + j * 16 + rsel;
            float bv = 0.f;
            if (mode == 0) bv = bias[nbase + cl];
            float vv[4];
#pragma unroll
            for (int rr = 0; rr < 4; rr++) {
                int rl = i * 16 + quad * 4 + rr;
                float x = acc[i * 2 + j][rr];
                if (mode == 0) x = fmaxf(x + bv, 0.f);
                else           x = theta * x + omt * bf2f(tH[rl * 136 + cl]);
                vv[rr] = x;
            }
#pragma unroll
            for (int rr = 0; rr < 4; rr++)
                tR[(i * 16 + quad * 4 + rr) * 136 + cl] = f2bf(vv[rr]);
            if (oTp) {
                ushort4 w4;
                w4.x = f2bf(vv[0]); w4.y = f2bf(vv[1]);
                w4.z = f2bf(vv[2]); w4.w = f2bf(vv[3]);
                *(ushort4*)&tT[cl * 72 + i * 16 + quad * 4] = w4;
            }
        }
    __syncthreads();
    {
        unsigned short* dst = oR + (size_t)(mbase + r) * DD + nbase + c0;
#pragma unroll
        for (int u = 0; u < 4; u++)
            *(uint4*)(dst + u * 8) = *(const uint4*)&tR[r * 136 + c0 + u * 8];
    }
    if (oTp) {
        int c = t >> 1, r0 = (t & 1) * 32;
        unsigned short* dst = oTp + (size_t)(nbase + c) * M3 + mbase + r0;
#pragma unroll
        for (int u = 0; u < 4; u++)
            *(uint4*)(dst + u * 8) = *(const uint4*)&tT[c * 72 + r0 + u * 8];
    }
}

// ---------- adj step on G: h = relu(0.9*(Ad@G + cv1.Gn1 + cv2.Gn2) + 0.1*P0) ----------
__global__ __launch_bounds__(256) void k_adj(
    const float* __restrict__ blk, const float* __restrict__ cross,
    const float* __restrict__ dinv,
    const unsigned short* __restrict__ GT, const unsigned short* __restrict__ Gr,
    const unsigned short* __restrict__ P0,
    unsigned short* __restrict__ hout, float* __restrict__ outF, int final_mode)
{
    __shared__ __align__(16) unsigned short AdL[64 * 64];    //  8 KB swizzled pitch-64
    __shared__ __align__(16) unsigned short GTL[256 * 64];   // 32 KB swizzled pitch-64
    __shared__ __align__(16) unsigned short OT[64 * 264];    // 33 KB out tile (mode 0)
    __shared__ float dv[64];
    int ch = blockIdx.x, d = blockIdx.y, m = blockIdx.z;
    int t = threadIdx.x;
    int lane = t & 63, wv = t >> 6;
    int dbase = d * 64, cbase = ch * 256;
    int rsel = lane & 15, quad = lane >> 4;

    if (t < 64) dv[t] = dinv[m * NTOT + dbase + t];
    __syncthreads();

    size_t bbase = (size_t)(m * N_DIA + d) * 4096;
#pragma unroll
    for (int q = 0; q < 4; q++) {
        int e4 = t + 256 * q;
        int i = e4 >> 4, j4 = e4 & 15;
        float4 w = *(const float4*)(blk + bbase + (size_t)i * 64 + j4 * 4);
        float di = dv[i];
        ushort4 o;
        o.x = f2bf(w.x * di * dv[j4 * 4 + 0]);
        o.y = f2bf(w.y * di * dv[j4 * 4 + 1]);
        o.z = f2bf(w.z * di * dv[j4 * 4 + 2]);
        o.w = f2bf(w.w * di * dv[j4 * 4 + 3]);
        *(ushort4*)((char*)AdL + i * 128 + (((j4 >> 1) ^ (i & 7)) << 4) + ((j4 & 1) << 3)) = o;
    }
#pragma unroll
    for (int p = 0; p < 8; p++) {
        int e = t + 256 * p;
        int cl = e >> 3;
        int uo = e & 7;
        uint4 w = *(const uint4*)(GT + (size_t)(cbase + cl) * M3 + m * NTOT + dbase + uo * 8);
        *(uint4*)((char*)GTL + cl * 128 + ((uo ^ (cl & 7)) << 4)) = w;
    }
    __syncthreads();

    f32x4 acc[16];
#pragma unroll
    for (int i = 0; i < 16; i++) acc[i] = (f32x4){0.f, 0.f, 0.f, 0.f};
#pragma unroll
    for (int kk = 0; kk < 2; kk++) {
        int su = ((kk * 4 + quad) ^ (rsel & 7)) << 4;
        frag8 bfr[4];
#pragma unroll
        for (int it = 0; it < 4; it++)
            bfr[it] = *(const frag8*)((const char*)AdL + (it * 16 + rsel) * 128 + su);
#pragma unroll
        for (int jc = 0; jc < 4; jc++) {
            frag8 af = *(const frag8*)((const char*)GTL + (wv * 64 + jc * 16 + rsel) * 128 + su);
#pragma unroll
            for (int it = 0; it < 4; it++)
                acc[jc * 4 + it] = __builtin_amdgcn_mfma_f32_16x16x32_bf16(
                    af, bfr[it], acc[jc * 4 + it], 0, 0, 0);
        }
    }

    int n1, n2, p1, p2;
    if (m == 0)      { n1 = 1; n2 = 2; p1 = 0; p2 = 1; }
    else if (m == 1) { n1 = 0; n2 = 2; p1 = 0; p2 = 2; }
    else             { n1 = 0; n2 = 1; p1 = 1; p2 = 2; }
#pragma unroll
    for (int it = 0; it < 4; it++) {
        int il = it * 16 + rsel;
        int gi = dbase + il;
        float dm = dv[il];
        float cv1 = cross[p1 * NTOT + gi] * dm * dinv[n1 * NTOT + gi];
        float cv2 = cross[p2 * NTOT + gi] * dm * dinv[n2 * NTOT + gi];
        size_t r1 = (size_t)(n1 * NTOT + gi) * DD;
        size_t r2 = (size_t)(n2 * NTOT + gi) * DD;
        size_t r0 = (size_t)(m * NTOT + gi) * DD;
#pragma unroll
        for (int jc = 0; jc < 4; jc++) {
            int cl = wv * 64 + jc * 16 + quad * 4;
            int cg = cbase + cl;
            ushort4 u1 = *(const ushort4*)(Gr + r1 + cg);
            ushort4 u2 = *(const ushort4*)(Gr + r2 + cg);
            ushort4 u0 = *(const ushort4*)(P0 + r0 + cg);
            f32x4 aa = acc[jc * 4 + it];
            float o0 = fmaxf(0.9f * (aa[0] + cv1 * bf2f(u1.x) + cv2 * bf2f(u2.x)) + 0.1f * bf2f(u0.x), 0.f);
            float o1 = fmaxf(0.9f * (aa[1] + cv1 * bf2f(u1.y) + cv2 * bf2f(u2.y)) + 0.1f * bf2f(u0.y), 0.f);
            float o2 = fmaxf(0.9f * (aa[2] + cv1 * bf2f(u1.z) + cv2 * bf2f(u2.z)) + 0.1f * bf2f(u0.z), 0.f);
            float o3 = fmaxf(0.9f * (aa[3] + cv1 * bf2f(u1.w) + cv2 * bf2f(u2.w)) + 0.1f * bf2f(u0.w), 0.f);
            if (final_mode) {
                *(float4*)(outF + (size_t)gi * 3072 + m * 1024 + 512 + cg) =
                    make_float4(o0, o1, o2, o3);
            } else {
                ushort4 w;
                w.x = f2bf(o0); w.y = f2bf(o1); w.z = f2bf(o2); w.w = f2bf(o3);
                *(ushort4*)&OT[il * 264 + cl] = w;
            }
        }
    }
    if (!final_mode) {
        __syncthreads();
        int r = t >> 2, c0 = (t & 3) * 64;
        unsigned short* dst = hout + (size_t)(m * NTOT + dbase + r) * DD + cbase + c0;
#pragma unroll
        for (int u = 0; u < 8; u++)
            *(uint4*)(dst + u * 8) = *(const uint4*)&OT[r * 264 + c0 + u * 8];
    }
}

extern "C" void kernel_launch(void* const* d_in, const int* in_sizes, int n_in,
                              void* d_out, int out_size, void* d_ws, size_t ws_size,
                              hipStream_t stream) {
    (void)in_sizes; (void)n_in; (void)out_size; (void)ws_size;
    const float* a     = (const float*)d_in[0];
    const float* v     = (const float*)d_in[1];
    const float* l     = (const float*)d_in[2];
    const float* qmask = (const float*)d_in[3];
    const float* Wspk  = (const float*)d_in[5];
    const float* W0    = (const float*)d_in[6];
    const float* b0    = (const float*)d_in[7];
    const float* Wg    = (const float*)d_in[8];
    float* out = (float*)d_out;
    float* ws = (float*)d_ws;

    float* invn  = ws;                                  // M3
    float* blk   = invn + M3;                           // 3*48*4096
    float* cross = blk + (size_t)3 * N_DIA * 4096;      // M3
    float* dinvp = cross + M3;                          // M3
    unsigned short* Wt  = (unsigned short*)(dinvp + M3);   // 3*DD*DD
    unsigned short* xb  = Wt + (size_t)3 * DD * DD;        // 3*SEG
    unsigned short* P02 = xb  + 3 * SEG;                   // 3*SEG (old h0 slot)
    unsigned short* G1r = P02 + 3 * SEG;                   // 3*SEG
    unsigned short* G1T = G1r + 3 * SEG;                   // 3*SEG
    unsigned short* h1  = G1T + 3 * SEG;                   // 3*SEG
    // lifetime aliases (total ws footprint identical to verified round-2 layout):
    unsigned short* G2r = xb;    // xb dead after k_fused013
    unsigned short* G2T = G1T;   // G1T dead after adj1

    const float th1 = 0.40546510810816438f;  // log(1.5)
    const float th2 = 0.22314355131420976f;  // log(1.25)

    k_pre_wt<<<1536, 256, 0, stream>>>(a, v, l, qmask, Wspk, W0, Wg, out, xb, invn, cross, Wt);
    // fused: h0 (LDS-only) -> G1 (rows+T) + P02 (rows); gram rides along as blocks 288..431
    k_fused013<<<432, 256, 0, stream>>>(xb, Wt, b0, G1r, G1T, P02,
                                        invn, cross, blk, dinvp, th1, th2);
    // h1 = relu(0.9*(Ad@G1 + cross terms) + 0.1*G1)
    k_adj<<<dim3(2, N_DIA, 3), 256, 0, stream>>>(blk, cross, dinvp, G1T, G1r, G1r,
                                                 h1, nullptr, 0);
    // G2 = th2*(h1@W2) + (1-th2)*h1 (rows + T)
    k_gemm<<<dim3(4, 144), 256, 0, stream>>>(h1, Wt + (size_t)2 * DD * DD, nullptr, G2r, G2T,
                                             th2, 1, nullptr, nullptr);
    // out_h = relu(0.9*(Ad@G2 + cross terms) + 0.1*P02) -> fp32 output
    k_adj<<<dim3(2, N_DIA, 3), 256, 0, stream>>>(blk, cross, dinvp, G2T, G2r, P02,
                                                 nullptr, out, 1);
}

// Round 4
// 199.674 us; speedup vs baseline: 1.2410x; 1.2410x over previous
//
#include <hip/hip_runtime.h>
#include <math.h>

#define N_DIA 48
#define NTOT  3072     // N utterances
#define DD    512      // D == H
#define M3    9216     // 3N
#define SEG   ((size_t)NTOT * DD)

#define SCALE_F 0.99999f
#define PI_F    3.14159274101257324f

typedef __attribute__((ext_vector_type(8))) short frag8;
typedef __attribute__((ext_vector_type(4))) float f32x4;

__device__ __forceinline__ float ang_sim(float cs) {
    float cc = cs * SCALE_F;
    cc = fminf(fmaxf(cc, -SCALE_F), SCALE_F);
    return 1.0f - acosf(cc) / PI_F;
}
__device__ __forceinline__ unsigned short f2bf(float x) {
    union { float f; unsigned int u; } c; c.f = x;
    unsigned int r = c.u + 0x7fffu + ((c.u >> 16) & 1u);
    return (unsigned short)(r >> 16);
}
__device__ __forceinline__ float bf2f(unsigned short h) {
    union { unsigned int u; float f; } c; c.u = ((unsigned int)h) << 16;
    return c.f;
}
__device__ __forceinline__ void gload16(const unsigned short* g, unsigned short* s) {
    __builtin_amdgcn_global_load_lds(
        (const __attribute__((address_space(1))) unsigned int*)g,
        (__attribute__((address_space(3))) unsigned int*)s, 16, 0, 0);
}

// ---------- K_pre_wt: (blocks 0..767) per-utterance pre; (768..1535) W -> bf16 [n][k] ----------
__global__ __launch_bounds__(256) void k_pre_wt(
    const float* __restrict__ a, const float* __restrict__ v,
    const float* __restrict__ l, const float* __restrict__ qmask,
    const float* __restrict__ Wspk, const float* __restrict__ W0,
    const float* __restrict__ Wg,
    float* __restrict__ out, unsigned short* __restrict__ xb,
    float* __restrict__ invn, float* __restrict__ cross,
    unsigned short* __restrict__ Wt)
{
    __shared__ float tile[32][33];
    int b = blockIdx.x;
    if (b < 768) {
        int wv = threadIdx.x >> 6, t = threadIdx.x & 63;
        int i = b * 4 + wv;                 // utterance, one wave each
        int pos = i & 63, dia = i >> 6;
        int qb = (pos * N_DIA + dia) * 2;
        float q0 = qmask[qb], q1 = qmask[qb + 1];
        int spk = (q0 >= q1) ? 0 : 1;
        const float4* av4 = (const float4*)(a + (size_t)i * DD);
        const float4* vv4 = (const float4*)(v + (size_t)i * DD);
        const float4* lv4 = (const float4*)(l + (size_t)i * DD);
        const float4* wv4 = (const float4*)(Wspk + (size_t)spk * DD);
        float* ob = out + (size_t)i * 3072;
        float saa = 0, svv = 0, sll = 0, sav = 0, sal = 0, svl = 0;
#pragma unroll
        for (int e = 0; e < 2; e++) {
            int idx = e * 64 + t;           // fully coalesced: lane-major
            float4 xa = av4[idx], xv = vv4[idx], xd = lv4[idx], xw = wv4[idx];
            float4 xL = make_float4(xd.x + xw.x, xd.y + xw.y, xd.z + xw.z, xd.w + xw.w);
            *(float4*)(ob + idx * 4)        = xa;
            *(float4*)(ob + 1024 + idx * 4) = xv;
            *(float4*)(ob + 2048 + idx * 4) = xL;
            ushort4 ya, yv, yl;
            ya.x = f2bf(xa.x); ya.y = f2bf(xa.y); ya.z = f2bf(xa.z); ya.w = f2bf(xa.w);
            yv.x = f2bf(xv.x); yv.y = f2bf(xv.y); yv.z = f2bf(xv.z); yv.w = f2bf(xv.w);
            yl.x = f2bf(xL.x); yl.y = f2bf(xL.y); yl.z = f2bf(xL.z); yl.w = f2bf(xL.w);
            *(ushort4*)(xb + (size_t)i * DD + idx * 4) = ya;
            *(ushort4*)(xb + SEG + (size_t)i * DD + idx * 4) = yv;
            *(ushort4*)(xb + 2 * SEG + (size_t)i * DD + idx * 4) = yl;
            saa += xa.x * xa.x + xa.y * xa.y + xa.z * xa.z + xa.w * xa.w;
            svv += xv.x * xv.x + xv.y * xv.y + xv.z * xv.z + xv.w * xv.w;
            sll += xL.x * xL.x + xL.y * xL.y + xL.z * xL.z + xL.w * xL.w;
            sav += xa.x * xv.x + xa.y * xv.y + xa.z * xv.z + xa.w * xv.w;
            sal += xa.x * xL.x + xa.y * xL.y + xa.z * xL.z + xa.w * xL.w;
            svl += xv.x * xL.x + xv.y * xL.y + xv.z * xL.z + xv.w * xL.w;
        }
#pragma unroll
        for (int off = 32; off; off >>= 1) {
            saa += __shfl_down(saa, off, 64);
            svv += __shfl_down(svv, off, 64);
            sll += __shfl_down(sll, off, 64);
            sav += __shfl_down(sav, off, 64);
            sal += __shfl_down(sal, off, 64);
            svl += __shfl_down(svl, off, 64);
        }
        if (t == 0) {
            float ina = 1.0f / sqrtf(saa);
            float inv_ = 1.0f / sqrtf(svv);
            float inl = 1.0f / sqrtf(sll);
            invn[i] = ina; invn[NTOT + i] = inv_; invn[2 * NTOT + i] = inl;
            cross[i]            = ang_sim(sav * ina * inv_);
            cross[NTOT + i]     = ang_sim(sal * ina * inl);
            cross[2 * NTOT + i] = ang_sim(svl * inv_ * inl);
        }
    } else {
        int idx = b - 768;
        int mm = idx >> 8;
        int by = (idx >> 4) & 15, bx = idx & 15;
        const float* W = (mm == 0) ? W0 : Wg + (size_t)(mm - 1) * DD * DD;
        int t = threadIdx.x, tx = t & 31, ty = t >> 5;
#pragma unroll
        for (int q = 0; q < 4; q++) {
            int k = by * 32 + ty + q * 8;
            tile[ty + q * 8][tx] = W[(size_t)k * DD + bx * 32 + tx];
        }
        __syncthreads();
#pragma unroll
        for (int q = 0; q < 4; q++) {
            int n = bx * 32 + ty + q * 8;
            Wt[(size_t)mm * DD * DD + (size_t)n * DD + by * 32 + tx] = f2bf(tile[tx][ty + q * 8]);
        }
    }
}

// ---------- gram (MFMA, swizzled LDS) + fused dinv ----------
__global__ __launch_bounds__(256) void k_gram_mfma(
    const unsigned short* __restrict__ xb, const float* __restrict__ invn,
    const float* __restrict__ cross, float* __restrict__ blk,
    float* __restrict__ dinv)
{
    __shared__ __align__(16) unsigned short Xs[16 * 2048];   // 64 KB
    int d = blockIdx.x, m = blockIdx.y;
    int t = threadIdx.x;
    int lane = t & 63, wv = t >> 6;
    int mrow = m * NTOT + d * 64;
    const unsigned short* src = xb + (size_t)mrow * DD;
    int sunit = ((t & 3) ^ ((t >> 2) & 3)) * 8;              // source pre-swizzle
#pragma unroll
    for (int c = 0; c < 16; c++) {
        gload16(src + (size_t)(t >> 2) * DD + c * 32 + sunit,
                &Xs[c * 2048 + wv * 512]);
    }
    __syncthreads();

    int rsel = lane & 15, quad = lane >> 4;
    int sq = (quad ^ (rsel & 3)) * 8;                        // swizzled read unit
    f32x4 acc[4];
#pragma unroll
    for (int j = 0; j < 4; j++) acc[j] = (f32x4){0.f, 0.f, 0.f, 0.f};
#pragma unroll
    for (int c = 0; c < 16; c++) {
        const unsigned short* base = &Xs[c * 2048];
        frag8 bf[4];
#pragma unroll
        for (int j = 0; j < 4; j++)
            bf[j] = *(const frag8*)&base[(j * 16 + rsel) * 32 + sq];
        frag8 af = *(const frag8*)&base[(wv * 16 + rsel) * 32 + sq];
#pragma unroll
        for (int j = 0; j < 4; j++)
            acc[j] = __builtin_amdgcn_mfma_f32_16x16x32_bf16(af, bf[j], acc[j], 0, 0, 0);
    }

    size_t bbase = (size_t)(m * N_DIA + d) * 4096;
    int rowl0 = wv * 16 + quad * 4;
    float ir[4], rs[4] = {0.f, 0.f, 0.f, 0.f};
#pragma unroll
    for (int r = 0; r < 4; r++) ir[r] = invn[mrow + rowl0 + r];
#pragma unroll
    for (int j = 0; j < 4; j++) {
        int coll = j * 16 + rsel;
        float ic = invn[mrow + coll];
#pragma unroll
        for (int r = 0; r < 4; r++) {
            float sim = ang_sim(acc[j][r] * ir[r] * ic);
            blk[bbase + (size_t)(rowl0 + r) * 64 + coll] = sim;
            rs[r] += sim;
        }
    }
#pragma unroll
    for (int off = 8; off; off >>= 1)
#pragma unroll
        for (int r = 0; r < 4; r++) rs[r] += __shfl_down(rs[r], off, 16);
    if (rsel == 0) {
#pragma unroll
        for (int r = 0; r < 4; r++) {
            int gi = d * 64 + rowl0 + r;
            float c1, c2;
            if (m == 0)      { c1 = cross[gi];        c2 = cross[NTOT + gi]; }
            else if (m == 1) { c1 = cross[gi];        c2 = cross[2 * NTOT + gi]; }
            else             { c1 = cross[NTOT + gi]; c2 = cross[2 * NTOT + gi]; }
            dinv[m * NTOT + gi] = 1.0f / sqrtf(rs[r] + c1 + c2);
        }
    }
}

// ---------- GEMM: 64(M) x 128(N) tile, dbuf LDS, swizzled, coalesced LDS epilogue ----------
// mode 0: relu(acc + bias[col])                 -> rows only
// mode 1: theta*acc + (1-theta)*A[row][col]     -> rows (+ optional transposed GT)
__global__ __launch_bounds__(256) void k_gemm(
    const unsigned short* __restrict__ A, const unsigned short* __restrict__ W,
    const float* __restrict__ bias,
    unsigned short* __restrict__ oRows, unsigned short* __restrict__ oT,
    float theta, int mode,
    const unsigned short* __restrict__ A2, unsigned short* __restrict__ oRows2)
{
    __shared__ __align__(16) char smem[53248];
    unsigned short* const As0 = (unsigned short*)smem;            // 4 KB
    unsigned short* const As1 = (unsigned short*)(smem + 4096);
    unsigned short* const Bs0 = (unsigned short*)(smem + 8192);   // 8 KB
    unsigned short* const Bs1 = (unsigned short*)(smem + 16384);
    unsigned short* const tH  = (unsigned short*)smem;            // [64][136]
    unsigned short* const tR  = (unsigned short*)(smem + 17408);  // [64][136]
    unsigned short* const tT  = (unsigned short*)(smem + 34816);  // [128][72]

    int t = threadIdx.x, lane = t & 63, wv = t >> 6;
    int bx = blockIdx.x, by = blockIdx.y;
    const unsigned short* Ap = A;
    unsigned short* oR = oRows;
    unsigned short* oTp = oT;
    if (by >= 144) { Ap = A2; oR = oRows2; oTp = nullptr; by -= 144; }
    int mbase = by * 64, nbase = bx * 128;
    int srow = lane >> 2;
    int scol = (((lane & 3) ^ (srow & 3)) * 8);
    int rsel = lane & 15, quad = lane >> 4;
    int sq = (quad ^ (rsel & 3)) * 8;

    const unsigned short* Ag  = Ap + (size_t)(mbase + wv * 16 + srow) * DD + scol;
    const unsigned short* Bg0 = W  + (size_t)(nbase + wv * 32 + srow) * DD + scol;
    const unsigned short* Bg1 = W  + (size_t)(nbase + wv * 32 + 16 + srow) * DD + scol;

    f32x4 acc[8];
#pragma unroll
    for (int i = 0; i < 8; i++) acc[i] = (f32x4){0.f, 0.f, 0.f, 0.f};

    gload16(Ag,  As0 + wv * 512);
    gload16(Bg0, Bs0 + wv * 1024);
    gload16(Bg1, Bs0 + wv * 1024 + 512);

#pragma unroll
    for (int kt = 0; kt < 16; kt++) {
        __syncthreads();
        const unsigned short* Ac = (kt & 1) ? As1 : As0;
        const unsigned short* Bc = (kt & 1) ? Bs1 : Bs0;
        if (kt < 15) {
            unsigned short* An = (kt & 1) ? As0 : As1;
            unsigned short* Bn = (kt & 1) ? Bs0 : Bs1;
            gload16(Ag + (kt + 1) * 32,  An + wv * 512);
            gload16(Bg0 + (kt + 1) * 32, Bn + wv * 1024);
            gload16(Bg1 + (kt + 1) * 32, Bn + wv * 1024 + 512);
        }
        frag8 af[4], bfr[2];
#pragma unroll
        for (int i = 0; i < 4; i++)
            af[i] = *(const frag8*)&Ac[(i * 16 + rsel) * 32 + sq];
#pragma unroll
        for (int j = 0; j < 2; j++)
            bfr[j] = *(const frag8*)&Bc[(wv * 32 + j * 16 + rsel) * 32 + sq];
#pragma unroll
        for (int i = 0; i < 4; i++)
#pragma unroll
            for (int j = 0; j < 2; j++)
                acc[i * 2 + j] = __builtin_amdgcn_mfma_f32_16x16x32_bf16(
                    af[i], bfr[j], acc[i * 2 + j], 0, 0, 0);
    }
    __syncthreads();

    int r = t >> 2, c0 = (t & 3) * 32;
    if (mode == 1) {
        const unsigned short* srcA = Ap + (size_t)(mbase + r) * DD + nbase + c0;
#pragma unroll
        for (int u = 0; u < 4; u++)
            *(uint4*)&tH[r * 136 + c0 + u * 8] = *(const uint4*)(srcA + u * 8);
        __syncthreads();
    }
    float omt = 1.0f - theta;
#pragma unroll
    for (int i = 0; i < 4; i++)
#pragma unroll
        for (int j = 0; j < 2; j++) {
            int cl = wv * 32 + j * 16 + rsel;
            float bv = 0.f;
            if (mode == 0) bv = bias[nbase + cl];
            float vv[4];
#pragma unroll
            for (int rr = 0; rr < 4; rr++) {
                int rl = i * 16 + quad * 4 + rr;
                float x = acc[i * 2 + j][rr];
                if (mode == 0) x = fmaxf(x + bv, 0.f);
                else           x = theta * x + omt * bf2f(tH[rl * 136 + cl]);
                vv[rr] = x;
            }
#pragma unroll
            for (int rr = 0; rr < 4; rr++)
                tR[(i * 16 + quad * 4 + rr) * 136 + cl] = f2bf(vv[rr]);
            if (oTp) {
                ushort4 w4;
                w4.x = f2bf(vv[0]); w4.y = f2bf(vv[1]);
                w4.z = f2bf(vv[2]); w4.w = f2bf(vv[3]);
                *(ushort4*)&tT[cl * 72 + i * 16 + quad * 4] = w4;
            }
        }
    __syncthreads();
    {
        unsigned short* dst = oR + (size_t)(mbase + r) * DD + nbase + c0;
#pragma unroll
        for (int u = 0; u < 4; u++)
            *(uint4*)(dst + u * 8) = *(const uint4*)&tR[r * 136 + c0 + u * 8];
    }
    if (oTp) {
        int c = t >> 1, r0 = (t & 1) * 32;
        unsigned short* dst = oTp + (size_t)(nbase + c) * M3 + mbase + r0;
#pragma unroll
        for (int u = 0; u < 4; u++)
            *(uint4*)(dst + u * 8) = *(const uint4*)&tT[c * 72 + r0 + u * 8];
    }
}

// ---------- adj step on G: h = relu(0.9*(Ad@G + cv1.Gn1 + cv2.Gn2) + 0.1*P0) ----------
// 128-col chunks: grid (4, N_DIA, 3) = 576 blocks, ~42 KB LDS -> 3 blocks/CU
// final_mode 0: write bf16 rows to hout; 1: write fp32 to out at [i*3072 + m*1024 + 512 + c]
__global__ __launch_bounds__(256) void k_adj(
    const float* __restrict__ blk, const float* __restrict__ cross,
    const float* __restrict__ dinv,
    const unsigned short* __restrict__ GT, const unsigned short* __restrict__ Gr,
    const unsigned short* __restrict__ P0,
    unsigned short* __restrict__ hout, float* __restrict__ outF, int final_mode)
{
    __shared__ __align__(16) unsigned short AdL[64 * 64];    //  8 KB swizzled pitch-64
    __shared__ __align__(16) unsigned short GTL[128 * 64];   // 16 KB swizzled pitch-64
    __shared__ __align__(16) unsigned short OT[64 * 136];    // 17 KB out tile (mode 0)
    __shared__ float dv[64];
    int ch = blockIdx.x, d = blockIdx.y, m = blockIdx.z;
    int t = threadIdx.x;
    int lane = t & 63, wv = t >> 6;
    int dbase = d * 64, cbase = ch * 128;
    int rsel = lane & 15, quad = lane >> 4;

    if (t < 64) dv[t] = dinv[m * NTOT + dbase + t];
    __syncthreads();

    // build Ad = dinv_i * blk * dinv_j (bf16, swizzled)
    size_t bbase = (size_t)(m * N_DIA + d) * 4096;
#pragma unroll
    for (int q = 0; q < 4; q++) {
        int e4 = t + 256 * q;
        int i = e4 >> 4, j4 = e4 & 15;
        float4 w = *(const float4*)(blk + bbase + (size_t)i * 64 + j4 * 4);
        float di = dv[i];
        ushort4 o;
        o.x = f2bf(w.x * di * dv[j4 * 4 + 0]);
        o.y = f2bf(w.y * di * dv[j4 * 4 + 1]);
        o.z = f2bf(w.z * di * dv[j4 * 4 + 2]);
        o.w = f2bf(w.w * di * dv[j4 * 4 + 3]);
        *(ushort4*)((char*)AdL + i * 128 + (((j4 >> 1) ^ (i & 7)) << 4) + ((j4 & 1) << 3)) = o;
    }
    // stage GT slice: 128 c-rows x 64 j (swizzled)
#pragma unroll
    for (int p = 0; p < 4; p++) {
        int e = t + 256 * p;               // 0..1023
        int cl = e >> 3;                   // 0..127
        int uo = e & 7;                    // 16-B unit 0..7
        uint4 w = *(const uint4*)(GT + (size_t)(cbase + cl) * M3 + m * NTOT + dbase + uo * 8);
        *(uint4*)((char*)GTL + cl * 128 + ((uo ^ (cl & 7)) << 4)) = w;
    }
    __syncthreads();

    f32x4 acc[8];
#pragma unroll
    for (int i = 0; i < 8; i++) acc[i] = (f32x4){0.f, 0.f, 0.f, 0.f};
#pragma unroll
    for (int kk = 0; kk < 2; kk++) {
        int su = ((kk * 4 + quad) ^ (rsel & 7)) << 4;
        frag8 bfr[4];
#pragma unroll
        for (int it = 0; it < 4; it++)
            bfr[it] = *(const frag8*)((const char*)AdL + (it * 16 + rsel) * 128 + su);
#pragma unroll
        for (int jc = 0; jc < 2; jc++) {
            frag8 af = *(const frag8*)((const char*)GTL + (wv * 32 + jc * 16 + rsel) * 128 + su);
#pragma unroll
            for (int it = 0; it < 4; it++)
                acc[jc * 4 + it] = __builtin_amdgcn_mfma_f32_16x16x32_bf16(
                    af, bfr[it], acc[jc * 4 + it], 0, 0, 0);
        }
    }

    int n1, n2, p1, p2;
    if (m == 0)      { n1 = 1; n2 = 2; p1 = 0; p2 = 1; }
    else if (m == 1) { n1 = 0; n2 = 2; p1 = 0; p2 = 2; }
    else             { n1 = 0; n2 = 1; p1 = 1; p2 = 2; }
#pragma unroll
    for (int it = 0; it < 4; it++) {
        int il = it * 16 + rsel;
        int gi = dbase + il;
        float dm = dv[il];
        float cv1 = cross[p1 * NTOT + gi] * dm * dinv[n1 * NTOT + gi];
        float cv2 = cross[p2 * NTOT + gi] * dm * dinv[n2 * NTOT + gi];
        size_t r1 = (size_t)(n1 * NTOT + gi) * DD;
        size_t r2 = (size_t)(n2 * NTOT + gi) * DD;
        size_t r0 = (size_t)(m * NTOT + gi) * DD;
#pragma unroll
        for (int jc = 0; jc < 2; jc++) {
            int cl = wv * 32 + jc * 16 + quad * 4;   // col within this 128-chunk
            int cg = cbase + cl;                     // global feature col
            ushort4 u1 = *(const ushort4*)(Gr + r1 + cg);
            ushort4 u2 = *(const ushort4*)(Gr + r2 + cg);
            ushort4 u0 = *(const ushort4*)(P0 + r0 + cg);
            f32x4 aa = acc[jc * 4 + it];
            float o0 = fmaxf(0.9f * (aa[0] + cv1 * bf2f(u1.x) + cv2 * bf2f(u2.x)) + 0.1f * bf2f(u0.x), 0.f);
            float o1 = fmaxf(0.9f * (aa[1] + cv1 * bf2f(u1.y) + cv2 * bf2f(u2.y)) + 0.1f * bf2f(u0.y), 0.f);
            float o2 = fmaxf(0.9f * (aa[2] + cv1 * bf2f(u1.z) + cv2 * bf2f(u2.z)) + 0.1f * bf2f(u0.z), 0.f);
            float o3 = fmaxf(0.9f * (aa[3] + cv1 * bf2f(u1.w) + cv2 * bf2f(u2.w)) + 0.1f * bf2f(u0.w), 0.f);
            if (final_mode) {
                *(float4*)(outF + (size_t)gi * 3072 + m * 1024 + 512 + cg) =
                    make_float4(o0, o1, o2, o3);
            } else {
                ushort4 w;
                w.x = f2bf(o0); w.y = f2bf(o1); w.z = f2bf(o2); w.w = f2bf(o3);
                *(ushort4*)&OT[il * 136 + cl] = w;
            }
        }
    }
    if (!final_mode) {
        __syncthreads();
        int r = t >> 2, c0 = (t & 3) * 32;
        unsigned short* dst = hout + (size_t)(m * NTOT + dbase + r) * DD + cbase + c0;
#pragma unroll
        for (int u = 0; u < 4; u++)
            *(uint4*)(dst + u * 8) = *(const uint4*)&OT[r * 136 + c0 + u * 8];
    }
}

extern "C" void kernel_launch(void* const* d_in, const int* in_sizes, int n_in,
                              void* d_out, int out_size, void* d_ws, size_t ws_size,
                              hipStream_t stream) {
    (void)in_sizes; (void)n_in; (void)out_size; (void)ws_size;
    const float* a     = (const float*)d_in[0];
    const float* v     = (const float*)d_in[1];
    const float* l     = (const float*)d_in[2];
    const float* qmask = (const float*)d_in[3];
    const float* Wspk  = (const float*)d_in[5];
    const float* W0    = (const float*)d_in[6];
    const float* b0    = (const float*)d_in[7];
    const float* Wg    = (const float*)d_in[8];
    float* out = (float*)d_out;
    float* ws = (float*)d_ws;

    float* invn  = ws;                                  // M3
    float* blk   = invn + M3;                           // 3*48*4096
    float* cross = blk + (size_t)3 * N_DIA * 4096;      // M3
    float* dinvp = cross + M3;                          // M3
    unsigned short* Wt  = (unsigned short*)(dinvp + M3);   // 3*DD*DD
    unsigned short* xb  = Wt + (size_t)3 * DD * DD;        // 3*SEG
    unsigned short* h0  = xb  + 3 * SEG;                   // 3*SEG
    unsigned short* G1r = h0  + 3 * SEG;                   // 3*SEG
    unsigned short* G1T = G1r + 3 * SEG;                   // 3*SEG
    unsigned short* h1  = G1T + 3 * SEG;                   // 3*SEG
    // lifetime aliases (total ws footprint identical to verified round-2 layout):
    unsigned short* G2r = xb;    // xb dead after gemm0; G2r born in gemm2
    unsigned short* G2T = G1r;   // G1r dead after adj1
    unsigned short* P02 = G1T;   // G1T dead after adj1

    const float th1 = 0.40546510810816438f;  // log(1.5)
    const float th2 = 0.22314355131420976f;  // log(1.25)

    k_pre_wt<<<1536, 256, 0, stream>>>(a, v, l, qmask, Wspk, W0, Wg, out, xb, invn, cross, Wt);
    k_gram_mfma<<<dim3(N_DIA, 3), 256, 0, stream>>>(xb, invn, cross, blk, dinvp);

    // h0 = relu(x @ W0 + b0)  (rows only)
    k_gemm<<<dim3(4, 144), 256, 0, stream>>>(xb, Wt, b0, h0, nullptr, 0.f, 0, nullptr, nullptr);
    // G1 = th1*(h0@W1) + (1-th1)*h0  (rows + transposed)
    k_gemm<<<dim3(4, 144), 256, 0, stream>>>(h0, Wt + (size_t)DD * DD, nullptr, G1r, G1T,
                                             th1, 1, nullptr, nullptr);
    // h1 = relu(0.9*(Ad@G1 + cross terms) + 0.1*G1)
    k_adj<<<dim3(4, N_DIA, 3), 256, 0, stream>>>(blk, cross, dinvp, G1T, G1r, G1r,
                                                 h1, nullptr, 0);
    // G2 = th2*(h1@W2) + (1-th2)*h1 (rows+T); P02 = th2*(h0@W2) + (1-th2)*h0 (rows, y>=144)
    k_gemm<<<dim3(4, 288), 256, 0, stream>>>(h1, Wt + (size_t)2 * DD * DD, nullptr, G2r, G2T,
                                             th2, 1, h0, P02);
    // out_h = relu(0.9*(Ad@G2 + cross terms) + 0.1*P02) -> fp32 output
    k_adj<<<dim3(4, N_DIA, 3), 256, 0, stream>>>(blk, cross, dinvp, G2T, G2r, P02,
                                                 nullptr, out, 1);
}